// Round 13
// baseline (8514.110 us; speedup 1.0000x reference)
//
#include <hip/hip_runtime.h>

#define Bz 64
#define Sz 512
#define Iz 512
#define Hz 1024
#define Lz 6
#define FB 520   // flag stride per layer

typedef __attribute__((ext_vector_type(8))) short bf16x8;
typedef __attribute__((ext_vector_type(4))) float f32x4;

__device__ __forceinline__ unsigned short f2bf(float f) {
  unsigned u = __float_as_uint(f);
  u += 0x7fffu + ((u >> 16) & 1u);
  return (unsigned short)(u >> 16);
}
__device__ __forceinline__ unsigned pkrnd(float lo, float hi) {
  return ((__float_as_uint(lo) + 0x8000u) >> 16) |
         ((__float_as_uint(hi) + 0x8000u) & 0xffff0000u);
}

// ---- asm helpers: LLC-direct (sc0 sc1 = bypass L1+L2) dataflow ----
template <int N>
__device__ __forceinline__ void vmwait() {
  asm volatile("s_waitcnt vmcnt(%0)" ::"n"(N) : "memory");
  __builtin_amdgcn_sched_barrier(0);
}
template <int OFF>
__device__ __forceinline__ uint4 ld16llc(const void* p) {
  uint4 r;
  asm volatile("global_load_dwordx4 %0, %1, off offset:%2 sc0 sc1"
               : "=&v"(r) : "v"(p), "n"(OFF));
  return r;
}
__device__ __forceinline__ float ldf_llc(const float* p) {
  float r;
  asm volatile("global_load_dword %0, %1, off sc0 sc1" : "=&v"(r) : "v"(p));
  return r;
}
__device__ __forceinline__ void stf_llc(float* p, float v) {
  asm volatile("global_store_dword %0, %1, off sc0 sc1" ::"v"(p), "v"(v) : "memory");
}
__device__ __forceinline__ void st2llc(void* p, unsigned v) {
  asm volatile("global_store_short %0, %1, off sc0 sc1" ::"v"(p), "v"(v) : "memory");
}

#define MFMA(a, b, c) __builtin_amdgcn_mfma_f32_16x16x32_bf16(a, b, c, 0, 0, 0)
#define BC(u) __builtin_bit_cast(bf16x8, u)

// Pre-swizzled bf16 weights: (col,k) stored at [col][k ^ ((col&7)<<3)] so a
// LINEAR global_load_lds produces the XOR-swizzled LDS tile directly.
__global__ void init_kernel(const float* __restrict__ wih, const float* __restrict__ bih,
                            const float* __restrict__ whh, const float* __restrict__ bhh,
                            const float* __restrict__ bout,
                            unsigned short* __restrict__ Wbf,
                            unsigned short* __restrict__ Wihbf,
                            unsigned int* __restrict__ hbuf32,
                            float* __restrict__ bias0, float* __restrict__ bias1,
                            float* __restrict__ out, int* __restrict__ flags, int nflags) {
  int tid = blockIdx.x * blockDim.x + threadIdx.x;
  int nt = gridDim.x * blockDim.x;
  for (int i = tid; i < Hz * Hz; i += nt) {
    int col = i >> 10, k = i & 1023;
    Wbf[(col << 10) | (k ^ ((col & 7) << 3))] = f2bf(whh[i]);
  }
  for (int i = tid; i < Hz * Iz; i += nt) {
    int col = i >> 9, k = i & 511;
    Wihbf[(col << 9) | (k ^ ((col & 7) << 3))] = f2bf(wih[i]);
  }
  for (int i = tid; i < (4 * Lz * Bz * Hz) / 2; i += nt) hbuf32[i] = 0u;  // 4-slot ring
  for (int i = tid; i < Hz; i += nt) {
    bias0[i] = bih[i] + bhh[i];   // layer 0
    bias1[i] = 2.0f * bhh[i];     // layers 1..5 (bias added twice in ref)
  }
  float b0 = bout[0];
  for (int i = tid; i < Bz * Sz; i += nt) out[i] = b0;
  for (int i = tid; i < nflags; i += nt) flags[i] = 0;
}

// Dual-stream cell GEMM (R8-exact ring, 2 output cols per lane-frag):
// 16 rows x 32 cols x K=1024. A1 = h[l-1]_t, A2 = h[l]_{t-1}, LLC-direct,
// 6-chunk-ahead counted vmcnt ring.
__device__ __forceinline__ void cell_gemm_d(const unsigned short* pA, const unsigned short* pB,
                                            const unsigned short* W0, const unsigned short* W1,
                                            int gg8, int ksw, f32x4 acc[2]) {
  uint4 A1a[16], A1b[16], A2a[16], A2b[16];
#define ISSD(c) { \
    A1a[c] = ld16llc<(c) * 128>(pA);      A1b[c] = ld16llc<(c) * 128 + 64>(pA); \
    A2a[c] = ld16llc<(c) * 128>(pB);      A2b[c] = ld16llc<(c) * 128 + 64>(pB); }
#define CKS(kofv, AFa, AFb) { const int kof = (kofv); \
    const bf16x8 b0 = *(const bf16x8*)(W0 + kof); \
    const bf16x8 b1 = *(const bf16x8*)(W1 + kof); \
    acc[0] = MFMA(AFa, b0, acc[0]); acc[1] = MFMA(AFa, b1, acc[1]); \
    acc[0] = MFMA(AFb, b0, acc[0]); acc[1] = MFMA(AFb, b1, acc[1]); }
#define CONSD(c) { \
    vmwait<4 * ((((c) + 6) < 16) ? 6 : 15 - (c))>(); \
    CKS((c) * 64 + (gg8 ^ ksw), BC(A1a[c]), BC(A2a[c])); \
    CKS((c) * 64 + ((32 + gg8) ^ ksw), BC(A1b[c]), BC(A2b[c])); }
  ISSD(0) ISSD(1) ISSD(2) ISSD(3) ISSD(4) ISSD(5)
  ISSD(6)  CONSD(0)  ISSD(7)  CONSD(1)  ISSD(8)  CONSD(2)
  ISSD(9)  CONSD(3)  ISSD(10) CONSD(4)  ISSD(11) CONSD(5)
  ISSD(12) CONSD(6)  ISSD(13) CONSD(7)  ISSD(14) CONSD(8)
  ISSD(15) CONSD(9)
  CONSD(10) CONSD(11) CONSD(12) CONSD(13) CONSD(14) CONSD(15)
#undef ISSD
#undef CONSD
#undef CKS
}

// Single-stream variant (layer 0): A = h[0]_{t-1}, 8-chunk-ahead ring (R8-exact).
__device__ __forceinline__ void cell_gemm_s(const unsigned short* pA,
                                            const unsigned short* W0, const unsigned short* W1,
                                            int gg8, int ksw, f32x4 acc[2]) {
  uint4 A1a[16], A1b[16];
#define ISSS(c) { \
    A1a[c] = ld16llc<(c) * 128>(pA);      A1b[c] = ld16llc<(c) * 128 + 64>(pA); }
#define CK1(kofv, AF) { const int kof = (kofv); \
    const bf16x8 b0 = *(const bf16x8*)(W0 + kof); \
    const bf16x8 b1 = *(const bf16x8*)(W1 + kof); \
    acc[0] = MFMA(AF, b0, acc[0]); acc[1] = MFMA(AF, b1, acc[1]); }
#define CONSS(c) { \
    vmwait<2 * ((((c) + 8) < 16) ? 8 : 15 - (c))>(); \
    CK1((c) * 64 + (gg8 ^ ksw), BC(A1a[c])); \
    CK1((c) * 64 + ((32 + gg8) ^ ksw), BC(A1b[c])); }
  ISSS(0) ISSS(1) ISSS(2) ISSS(3) ISSS(4) ISSS(5) ISSS(6) ISSS(7)
  ISSS(8)  CONSS(0)  ISSS(9)  CONSS(1)  ISSS(10) CONSS(2)  ISSS(11) CONSS(3)
  ISSS(12) CONSS(4)  ISSS(13) CONSS(5)  ISSS(14) CONSS(6)  ISSS(15) CONSS(7)
  CONSS(8) CONSS(9) CONSS(10) CONSS(11) CONSS(12) CONSS(13) CONSS(14) CONSS(15)
#undef ISSS
#undef CONSS
#undef CK1
}

// Persistent self-timed wavefront kernel, placement-independent. R8 structure,
// SPLIT-N: 32 WGs/layer x 32 cols (64 KB W slice -> 2 WGs/CU, 8 waves/CU).
// Blocks 0..191: layer = bid>>5, col tile = bid&31. Flag counts: F to 32.
// Blocks 192..207: xproj (xq[t&3] = x_t @ W_ih^T, 4 beats ahead), X to 16.
// All cross-WG h/xq data LLC-direct (sc0 sc1); no cache fences anywhere.
__global__ __launch_bounds__(256, 1) void rnn_kernel(
    const float* __restrict__ x,
    const unsigned short* __restrict__ Wbf,
    const unsigned short* __restrict__ Wihbf,
    unsigned short* __restrict__ hbuf, float* __restrict__ xq,
    const float* __restrict__ bias0, const float* __restrict__ bias1,
    const float* __restrict__ wout,
    float* __restrict__ dout, int* __restrict__ F, int* __restrict__ X) {
  extern __shared__ char lds[];
  unsigned short* Wl = (unsigned short*)lds;   // [32][1024] (layer) / [64][512] (xproj)

  const int bid = blockIdx.x;
  const int tid = threadIdx.x;
  const int lane = tid & 63;
  const int wav = tid >> 6;
  const int cc = lane & 15;
  const int gg = lane >> 4;
  const int gg8 = gg << 3;
  const int ksw = (cc & 7) << 3;
  const int ra = wav * 16 + cc;  // A row this lane gathers

  if (bid < 192) {
    // ================= layer worker =================
    const int layer = bid >> 5;
    const int c0 = (bid & 31) << 5;  // 32 output cols
    {
      const unsigned short* wsrc = Wbf + ((size_t)c0 << 10);
      for (int i = 0; i < 16; ++i) {
        const int off = (i * 256 + tid) * 8;
        __builtin_amdgcn_global_load_lds(wsrc + off, Wl + off, 16, 0, 0);
      }
      asm volatile("s_waitcnt vmcnt(0)" ::: "memory");
    }
    __syncthreads();
    float bv[2], wv[2];
#pragma unroll
    for (int n = 0; n < 2; ++n) {
      const int col = c0 + n * 16 + cc;
      bv[n] = (layer == 0) ? bias0[col] : bias1[col];
      wv[n] = (layer == Lz - 1) ? wout[col] : 0.f;
    }
    const unsigned short* W0 = Wl + (0 * 16 + cc) * 1024;
    const unsigned short* W1 = Wl + (1 * 16 + cc) * 1024;

    for (int t = 0; t < Sz; ++t) {
      const int b = t + layer;
      // ---- gate: lane-parallel poll (R8-exact logic; F counts to 32)
      if (wav == 0) {
        const int* fp = nullptr;
        int tgt = 32;
        if (lane == 0) {
          if (layer == 0) { fp = &X[t]; tgt = 16; }
          else fp = &F[(layer - 1) * FB + (b - 1)];
        }
        if (lane == 1 && t >= 1) fp = &F[layer * FB + (b - 1)];
        if (lane == 2 && layer < Lz - 1 && t >= 4) fp = &F[(layer + 1) * FB + (b - 3)];
        if (fp) {
          while (__hip_atomic_load(fp, __ATOMIC_RELAXED, __HIP_MEMORY_SCOPE_AGENT) < tgt)
            __builtin_amdgcn_s_sleep(1);
        }
      }
      __syncthreads();

      const unsigned short* hrd = hbuf + (size_t)(b & 3) * (Lz * Bz * Hz);
      unsigned short* hwr = hbuf + (size_t)((b + 1) & 3) * (Lz * Bz * Hz);

      f32x4 acc[2];
#pragma unroll
      for (int n = 0; n < 2; ++n) acc[n] = (f32x4){0.f, 0.f, 0.f, 0.f};
      if (layer == 0) {
        const unsigned short* pA = hrd + (size_t)ra * Hz + gg8;
        cell_gemm_s(pA, W0, W1, gg8, ksw, acc);
      } else {
        const unsigned short* pA =
            hrd + ((size_t)((layer - 1) * Bz + ra)) * Hz + gg8;
        const unsigned short* pB =
            hrd + ((size_t)(layer * Bz + ra)) * Hz + gg8;
        cell_gemm_d(pA, pB, W0, W1, gg8, ksw, acc);
      }

      // ---- epilogue (layer 0: add xproj, LLC-direct loads)
      float xv[8];
      if (layer == 0) {
        const float* xb = xq + (size_t)(t & 3) * (Bz * Hz);
#pragma unroll
        for (int n = 0; n < 2; ++n)
#pragma unroll
          for (int i = 0; i < 4; ++i) {
            const int brow = wav * 16 + gg * 4 + i;
            xv[n * 4 + i] = ldf_llc(xb + (size_t)brow * Hz + c0 + n * 16 + cc);
          }
        vmwait<0>();
      }
      float hv[2][4];
#pragma unroll
      for (int n = 0; n < 2; ++n) {
        const int col = c0 + n * 16 + cc;
#pragma unroll
        for (int i = 0; i < 4; ++i) {
          const int brow = wav * 16 + gg * 4 + i;
          float z = acc[n][i] + bv[n];
          if (layer == 0) z += xv[n * 4 + i];
          const float v = tanhf(z);
          hv[n][i] = v;
          st2llc(hwr + ((size_t)layer * Bz + brow) * Hz + col, (unsigned)f2bf(v));
          if (t == Sz - 1)
            dout[Bz * Sz + ((size_t)layer * Bz + brow) * Hz + col] = v;
        }
      }
      if (layer == Lz - 1) {
#pragma unroll
        for (int i = 0; i < 4; ++i) {
          float pv = hv[0][i] * wv[0] + hv[1][i] * wv[1];
          pv += __shfl_xor(pv, 1);
          pv += __shfl_xor(pv, 2);
          pv += __shfl_xor(pv, 4);
          pv += __shfl_xor(pv, 8);
          if (cc == 0) {
            const int brow = wav * 16 + gg * 4 + i;
            atomicAdd(&dout[(size_t)brow * Sz + t], pv);
          }
        }
      }
      // ---- release: drain write-through stores, then LLC flag RMW
      asm volatile("s_waitcnt vmcnt(0)" ::: "memory");
      __syncthreads();
      if (tid == 0)
        __hip_atomic_fetch_add(&F[layer * FB + b], 1, __ATOMIC_RELEASE,
                               __HIP_MEMORY_SCOPE_AGENT);
    }
  } else {
    // ================= xproj worker (R8-exact) =================
    const int xc0 = (bid - 192) << 6;  // 64 cols of H
    {
      const unsigned short* wsrc = Wihbf + ((size_t)xc0 << 9);
      for (int i = 0; i < 16; ++i) {
        const int off = (i * 256 + tid) * 8;
        __builtin_amdgcn_global_load_lds(wsrc + off, Wl + off, 16, 0, 0);
      }
      asm volatile("s_waitcnt vmcnt(0)" ::: "memory");
    }
    __syncthreads();

    for (int tx = 0; tx < Sz; ++tx) {
      if (tx >= 4) {  // xq ring WAR guard (F now counts to 32)
        if (tid == 0) {
          while (__hip_atomic_load(&F[0 * FB + (tx - 4)], __ATOMIC_RELAXED,
                                   __HIP_MEMORY_SCOPE_AGENT) < 32)
            __builtin_amdgcn_s_sleep(1);
        }
        __syncthreads();
      }
      const float* xrow = x + ((size_t)ra * Sz + tx) * Iz + gg8;
      f32x4 acc[4];
#pragma unroll
      for (int n = 0; n < 4; ++n) acc[n] = (f32x4){0.f, 0.f, 0.f, 0.f};
      float4 xr[3][4];
#pragma unroll
      for (int c = 0; c < 2; ++c)
#pragma unroll
        for (int q = 0; q < 2; ++q) {
          xr[c][2 * q + 0] = *(const float4*)(xrow + c * 64 + q * 32);
          xr[c][2 * q + 1] = *(const float4*)(xrow + c * 64 + q * 32 + 4);
        }
#pragma unroll
      for (int c = 0; c < 8; ++c) {
        if (c + 2 < 8) {
          const int s2 = (c + 2) % 3;
#pragma unroll
          for (int q = 0; q < 2; ++q) {
            xr[s2][2 * q + 0] = *(const float4*)(xrow + (c + 2) * 64 + q * 32);
            xr[s2][2 * q + 1] = *(const float4*)(xrow + (c + 2) * 64 + q * 32 + 4);
          }
        }
        const int s = c % 3;
#pragma unroll
        for (int ks = 0; ks < 2; ++ks) {
          const float4 f0 = xr[s][2 * ks + 0];
          const float4 f1 = xr[s][2 * ks + 1];
          uint4 pk;
          pk.x = pkrnd(f0.x, f0.y);
          pk.y = pkrnd(f0.z, f0.w);
          pk.z = pkrnd(f1.x, f1.y);
          pk.w = pkrnd(f1.z, f1.w);
          const bf16x8 af = BC(pk);
          const int kof = c * 64 + ((ks * 32 + gg8) ^ ksw);
#pragma unroll
          for (int n = 0; n < 4; ++n) {
            const bf16x8 bf = *(const bf16x8*)(Wl + (n * 16 + cc) * 512 + kof);
            acc[n] = MFMA(af, bf, acc[n]);
          }
        }
      }
      float* xdst = xq + (size_t)(tx & 3) * (Bz * Hz);
#pragma unroll
      for (int n = 0; n < 4; ++n)
#pragma unroll
        for (int i = 0; i < 4; ++i) {
          const int brow = wav * 16 + gg * 4 + i;
          stf_llc(xdst + (size_t)brow * Hz + xc0 + n * 16 + cc, acc[n][i]);
        }
      asm volatile("s_waitcnt vmcnt(0)" ::: "memory");
      __syncthreads();
      if (tid == 0)
        __hip_atomic_fetch_add(&X[tx], 1, __ATOMIC_RELEASE, __HIP_MEMORY_SCOPE_AGENT);
    }
  }
}

extern "C" void kernel_launch(void* const* d_in, const int* in_sizes, int n_in,
                              void* d_out, int out_size, void* d_ws, size_t ws_size,
                              hipStream_t stream) {
  (void)in_sizes; (void)n_in; (void)out_size; (void)ws_size;
  const float* x    = (const float*)d_in[0];
  const float* wih  = (const float*)d_in[1];
  const float* bih  = (const float*)d_in[2];
  const float* whh  = (const float*)d_in[3];
  const float* bhh  = (const float*)d_in[4];
  const float* wout = (const float*)d_in[5];
  const float* bout = (const float*)d_in[6];
  float* out = (float*)d_out;
  char* ws = (char*)d_ws;
  // ws: [0,2M) Wbf | [2M,3M) Wihbf | [3M,6M) h ring bf16[4][L][B][H] |
  //     [6M,7M) xq ring f32[4][B][H] | [7M,+8K) bias0/1 | [7M+16K) flags
  unsigned short* Wbf   = (unsigned short*)(ws);
  unsigned short* Wihbf = (unsigned short*)(ws + ((size_t)2 << 20));
  unsigned short* hbuf  = (unsigned short*)(ws + ((size_t)3 << 20));
  float* xq    = (float*)(ws + ((size_t)6 << 20));
  float* bias0 = (float*)(ws + ((size_t)7 << 20));
  float* bias1 = bias0 + Hz;
  int* F = (int*)(ws + ((size_t)7 << 20) + 16384);  // [6][FB]
  int* X = F + Lz * FB;                             // [512]
  const int nflags = Lz * FB + Sz;

  (void)hipFuncSetAttribute((const void*)rnn_kernel,
                            hipFuncAttributeMaxDynamicSharedMemorySize, 65536);
  (void)hipGetLastError();

  hipLaunchKernelGGL(init_kernel, dim3(1024), dim3(256), 0, stream,
                     wih, bih, whh, bhh, bout, Wbf, Wihbf,
                     (unsigned int*)hbuf, bias0, bias1, out, F, nflags);
  hipLaunchKernelGGL(rnn_kernel, dim3(208), dim3(256), 65536, stream,
                     x, Wbf, Wihbf, hbuf, xq, bias0, bias1, wout, out, F, X);
}

// Round 14
// 6879.839 us; speedup vs baseline: 1.2375x; 1.2375x over previous
//
#include <hip/hip_runtime.h>

#define Bz 64
#define Sz 512
#define Iz 512
#define Hz 1024
#define Lz 6
#define CPAD 32   // ints per counter cacheline (128 B)

typedef __attribute__((ext_vector_type(8))) short bf16x8;
typedef __attribute__((ext_vector_type(4))) float f32x4;

__device__ __forceinline__ unsigned short f2bf(float f) {
  unsigned u = __float_as_uint(f);
  u += 0x7fffu + ((u >> 16) & 1u);
  return (unsigned short)(u >> 16);
}
__device__ __forceinline__ unsigned pkrnd(float lo, float hi) {
  return ((__float_as_uint(lo) + 0x8000u) >> 16) |
         ((__float_as_uint(hi) + 0x8000u) & 0xffff0000u);
}

// ---- asm helpers: LLC-direct (sc0 sc1 = bypass L1+L2) dataflow ----
template <int N>
__device__ __forceinline__ void vmwait() {
  asm volatile("s_waitcnt vmcnt(%0)" ::"n"(N) : "memory");
  __builtin_amdgcn_sched_barrier(0);
}
template <int OFF>
__device__ __forceinline__ uint4 ld16llc(const void* p) {
  uint4 r;
  asm volatile("global_load_dwordx4 %0, %1, off offset:%2 sc0 sc1"
               : "=&v"(r) : "v"(p), "n"(OFF));
  return r;
}
__device__ __forceinline__ float ldf_llc(const float* p) {
  float r;
  asm volatile("global_load_dword %0, %1, off sc0 sc1" : "=&v"(r) : "v"(p));
  return r;
}
__device__ __forceinline__ void stf_llc(float* p, float v) {
  asm volatile("global_store_dword %0, %1, off sc0 sc1" ::"v"(p), "v"(v) : "memory");
}
__device__ __forceinline__ void st2llc(void* p, unsigned v) {
  asm volatile("global_store_short %0, %1, off sc0 sc1" ::"v"(p), "v"(v) : "memory");
}

#define MFMA(a, b, c) __builtin_amdgcn_mfma_f32_16x16x32_bf16(a, b, c, 0, 0, 0)
#define BC(u) __builtin_bit_cast(bf16x8, u)

// Pre-swizzled bf16 weights: (col,k) stored at [col][k ^ ((col&7)<<3)] so a
// LINEAR global_load_lds produces the XOR-swizzled LDS tile directly.
__global__ void init_kernel(const float* __restrict__ wih, const float* __restrict__ bih,
                            const float* __restrict__ whh, const float* __restrict__ bhh,
                            const float* __restrict__ bout,
                            unsigned short* __restrict__ Wbf,
                            unsigned short* __restrict__ Wihbf,
                            unsigned int* __restrict__ hbuf32,
                            float* __restrict__ bias0, float* __restrict__ bias1,
                            float* __restrict__ out, int* __restrict__ flags, int nflags) {
  int tid = blockIdx.x * blockDim.x + threadIdx.x;
  int nt = gridDim.x * blockDim.x;
  for (int i = tid; i < Hz * Hz; i += nt) {
    int col = i >> 10, k = i & 1023;
    Wbf[(col << 10) | (k ^ ((col & 7) << 3))] = f2bf(whh[i]);
  }
  for (int i = tid; i < Hz * Iz; i += nt) {
    int col = i >> 9, k = i & 511;
    Wihbf[(col << 9) | (k ^ ((col & 7) << 3))] = f2bf(wih[i]);
  }
  for (int i = tid; i < (4 * Lz * Bz * Hz) / 2; i += nt) hbuf32[i] = 0u;  // 4-slot ring
  for (int i = tid; i < Hz; i += nt) {
    bias0[i] = bih[i] + bhh[i];   // layer 0
    bias1[i] = 2.0f * bhh[i];     // layers 1..5 (bias added twice in ref)
  }
  float b0 = bout[0];
  for (int i = tid; i < Bz * Sz; i += nt) out[i] = b0;
  for (int i = tid; i < nflags; i += nt) flags[i] = 0;
}

// Dual-stream cell GEMM: 16 rows(this wave) x 64 cols x K=1024,
// A1 = h[l-1]_t, A2 = h[l]_{t-1}, LLC-direct, 8-chunk-ahead counted ring.
__device__ __forceinline__ void cell_gemm_d(const unsigned short* pA, const unsigned short* pB,
                                            const unsigned short* Wl, int cc, int gg,
                                            f32x4 acc[4]) {
  const int ksw = (cc & 7) << 3;
  const int gg8 = gg << 3;
  const unsigned short* Wl0 = Wl + (0 * 16 + cc) * 1024;
  const unsigned short* Wl1 = Wl + (1 * 16 + cc) * 1024;
  const unsigned short* Wl2 = Wl + (2 * 16 + cc) * 1024;
  const unsigned short* Wl3 = Wl + (3 * 16 + cc) * 1024;
  uint4 A1a[16], A1b[16], A2a[16], A2b[16];
#define ISSD(c) { \
    A1a[c] = ld16llc<(c) * 128>(pA);      A1b[c] = ld16llc<(c) * 128 + 64>(pA); \
    A2a[c] = ld16llc<(c) * 128>(pB);      A2b[c] = ld16llc<(c) * 128 + 64>(pB); }
#define CONS_KS(kofv, AFa, AFb) { \
    const int kof = (kofv); \
    const bf16x8 bA = *(const bf16x8*)(Wl0 + kof); \
    const bf16x8 bB = *(const bf16x8*)(Wl1 + kof); \
    const bf16x8 bC = *(const bf16x8*)(Wl2 + kof); \
    const bf16x8 bD = *(const bf16x8*)(Wl3 + kof); \
    acc[0] = MFMA(AFa, bA, acc[0]); acc[1] = MFMA(AFa, bB, acc[1]); \
    acc[2] = MFMA(AFa, bC, acc[2]); acc[3] = MFMA(AFa, bD, acc[3]); \
    acc[0] = MFMA(AFb, bA, acc[0]); acc[1] = MFMA(AFb, bB, acc[1]); \
    acc[2] = MFMA(AFb, bC, acc[2]); acc[3] = MFMA(AFb, bD, acc[3]); }
#define CONSD(c) { \
    vmwait<4 * ((((c) + 8) < 16) ? 8 : 15 - (c))>(); \
    CONS_KS((c) * 64 + (gg8 ^ ksw), BC(A1a[c]), BC(A2a[c])); \
    CONS_KS((c) * 64 + ((32 + gg8) ^ ksw), BC(A1b[c]), BC(A2b[c])); }
  ISSD(0) ISSD(1) ISSD(2) ISSD(3) ISSD(4) ISSD(5) ISSD(6) ISSD(7)
  ISSD(8)  CONSD(0)  ISSD(9)  CONSD(1)  ISSD(10) CONSD(2)
  ISSD(11) CONSD(3)  ISSD(12) CONSD(4)  ISSD(13) CONSD(5)
  ISSD(14) CONSD(6)  ISSD(15) CONSD(7)
  CONSD(8) CONSD(9) CONSD(10) CONSD(11) CONSD(12) CONSD(13) CONSD(14) CONSD(15)
#undef ISSD
#undef CONSD
#undef CONS_KS
}

// Single-stream variant (layer 0): A1 = h[0]_{t-1}, 8-chunk-ahead ring (R8-exact).
__device__ __forceinline__ void cell_gemm_s(const unsigned short* pA,
                                            const unsigned short* Wl, int cc, int gg,
                                            f32x4 acc[4]) {
  const int ksw = (cc & 7) << 3;
  const int gg8 = gg << 3;
  const unsigned short* Wl0 = Wl + (0 * 16 + cc) * 1024;
  const unsigned short* Wl1 = Wl + (1 * 16 + cc) * 1024;
  const unsigned short* Wl2 = Wl + (2 * 16 + cc) * 1024;
  const unsigned short* Wl3 = Wl + (3 * 16 + cc) * 1024;
  uint4 A1a[16], A1b[16];
#define ISSS(c) { \
    A1a[c] = ld16llc<(c) * 128>(pA);      A1b[c] = ld16llc<(c) * 128 + 64>(pA); }
#define CONS_K1(kofv, AF) { \
    const int kof = (kofv); \
    const bf16x8 bA = *(const bf16x8*)(Wl0 + kof); \
    const bf16x8 bB = *(const bf16x8*)(Wl1 + kof); \
    const bf16x8 bC = *(const bf16x8*)(Wl2 + kof); \
    const bf16x8 bD = *(const bf16x8*)(Wl3 + kof); \
    acc[0] = MFMA(AF, bA, acc[0]); acc[1] = MFMA(AF, bB, acc[1]); \
    acc[2] = MFMA(AF, bC, acc[2]); acc[3] = MFMA(AF, bD, acc[3]); }
#define CONSS(c) { \
    vmwait<2 * ((((c) + 8) < 16) ? 8 : 15 - (c))>(); \
    CONS_K1((c) * 64 + (gg8 ^ ksw), BC(A1a[c])); \
    CONS_K1((c) * 64 + ((32 + gg8) ^ ksw), BC(A1b[c])); }
  ISSS(0) ISSS(1) ISSS(2) ISSS(3) ISSS(4) ISSS(5) ISSS(6) ISSS(7)
  ISSS(8)  CONSS(0)  ISSS(9)  CONSS(1)  ISSS(10) CONSS(2)  ISSS(11) CONSS(3)
  ISSS(12) CONSS(4)  ISSS(13) CONSS(5)  ISSS(14) CONSS(6)  ISSS(15) CONSS(7)
  CONSS(8) CONSS(9) CONSS(10) CONSS(11) CONSS(12) CONSS(13) CONSS(14) CONSS(15)
#undef ISSS
#undef CONSS
#undef CONS_K1
}

// Persistent self-timed wavefront kernel (R8 structure, placement-independent).
// Blocks 0..95: layer = bid>>4, 64-col tile j = bid&15; W_hh slice LDS-resident.
// Blocks 96..111: xproj (xq[t&3] = x_t @ W_ih^T, 4 beats ahead).
// FLAGS (changed from R8): single-writer padded beat counters, one cacheline
// per WG: C[l][j] = timesteps completed by layer-WG (l,j); Xc[j] for xproj.
// Gate conditions = exact translation of R8's F/X conditions:
//   upstream  C[l-1][j] >= t+1   (R8: F[l-1][b-1] >= 16)
//   own       C[l][j]   >= t     (R8: F[l][b-1]   >= 16)
//   WAR       C[l+1][j] >= t-3   (R8: F[l+1][b-3] >= 16)
//   xq ready  Xc[j]     >= t+1   (R8: X[t] >= 16)
//   xproj WAR C[0][j]   >= tx-3  (R8: F[0][tx-4] >= 16)
// Releases: own-cell fetch_add(1, RELEASE) -- single writer, no contention.
__global__ __launch_bounds__(256, 1) void rnn_kernel(
    const float* __restrict__ x,
    const unsigned short* __restrict__ Wbf,
    const unsigned short* __restrict__ Wihbf,
    unsigned short* __restrict__ hbuf, float* __restrict__ xq,
    const float* __restrict__ bias0, const float* __restrict__ bias1,
    const float* __restrict__ wout,
    float* __restrict__ dout, int* __restrict__ C, int* __restrict__ Xc) {
  extern __shared__ char lds[];
  unsigned short* Wl = (unsigned short*)lds;

  const int bid = blockIdx.x;
  const int tid = threadIdx.x;
  const int lane = tid & 63;
  const int wav = tid >> 6;
  const int cc = lane & 15;
  const int gg = lane >> 4;
  const int ra = wav * 16 + cc;  // A row this lane gathers

  if (bid < 96) {
    // ================= layer worker =================
    const int layer = bid >> 4;
    const int jself = bid & 15;
    const int c0 = jself << 6;  // 64 output cols
    {
      const unsigned short* wsrc = Wbf + ((size_t)c0 << 10);
      for (int i = 0; i < 32; ++i) {
        const int off = (i * 256 + tid) * 8;
        __builtin_amdgcn_global_load_lds(wsrc + off, Wl + off, 16, 0, 0);
      }
      asm volatile("s_waitcnt vmcnt(0)" ::: "memory");
    }
    __syncthreads();
    float bv[4], wv[4];
#pragma unroll
    for (int n = 0; n < 4; ++n) {
      const int col = c0 + n * 16 + cc;
      bv[n] = (layer == 0) ? bias0[col] : bias1[col];
      wv[n] = (layer == Lz - 1) ? wout[col] : 0.f;
    }
    int* Cown = &C[(layer * 16 + jself) * CPAD];

    for (int t = 0; t < Sz; ++t) {
      const int b = t + layer;
      // ---- WG-wide gate: wave 0, lane-parallel single poll loop
      if (wav == 0) {
        const int* gp = nullptr;
        int tgt = 0;
        const int j = lane & 15;
        if (lane < 16) {                       // upstream producers
          if (layer > 0) { gp = &C[((layer - 1) * 16 + j) * CPAD]; tgt = t + 1; }
          else           { gp = &Xc[j * CPAD];                      tgt = t + 1; }
        } else if (lane < 32) {                // own layer, prev beat
          if (t >= 1)    { gp = &C[(layer * 16 + j) * CPAD];        tgt = t; }
        } else if (lane < 48) {                // downstream WAR
          if (layer < Lz - 1 && t >= 4) { gp = &C[((layer + 1) * 16 + j) * CPAD]; tgt = t - 3; }
        }
        for (;;) {
          bool ok = true;
          if (gp)
            ok = __hip_atomic_load(gp, __ATOMIC_RELAXED, __HIP_MEMORY_SCOPE_AGENT) >= tgt;
          if (__all(ok)) break;
          __builtin_amdgcn_s_sleep(1);
        }
      }
      __syncthreads();

      const unsigned short* hrd = hbuf + (size_t)(b & 3) * (Lz * Bz * Hz);
      unsigned short* hwr = hbuf + (size_t)((b + 1) & 3) * (Lz * Bz * Hz);

      f32x4 acc[4];
#pragma unroll
      for (int n = 0; n < 4; ++n) acc[n] = (f32x4){0.f, 0.f, 0.f, 0.f};
      if (layer == 0) {
        const unsigned short* pA = hrd + (size_t)ra * Hz + (gg << 3);
        cell_gemm_s(pA, Wl, cc, gg, acc);
      } else {
        const unsigned short* pA =
            hrd + ((size_t)((layer - 1) * Bz + ra)) * Hz + (gg << 3);
        const unsigned short* pB =
            hrd + ((size_t)(layer * Bz + ra)) * Hz + (gg << 3);
        cell_gemm_d(pA, pB, Wl, cc, gg, acc);
      }

      // ---- epilogue (layer 0: add xproj, LLC-direct loads)
      float xv[16];
      if (layer == 0) {
        const float* xb = xq + (size_t)(t & 3) * (Bz * Hz);
#pragma unroll
        for (int n = 0; n < 4; ++n)
#pragma unroll
          for (int i = 0; i < 4; ++i) {
            const int brow = wav * 16 + gg * 4 + i;
            xv[n * 4 + i] = ldf_llc(xb + (size_t)brow * Hz + c0 + n * 16 + cc);
          }
        vmwait<0>();
      }
      float hv[4][4];
#pragma unroll
      for (int n = 0; n < 4; ++n) {
        const int col = c0 + n * 16 + cc;
#pragma unroll
        for (int i = 0; i < 4; ++i) {
          const int brow = wav * 16 + gg * 4 + i;
          float z = acc[n][i] + bv[n];
          if (layer == 0) z += xv[n * 4 + i];
          const float v = tanhf(z);
          hv[n][i] = v;
          st2llc(hwr + ((size_t)layer * Bz + brow) * Hz + col, (unsigned)f2bf(v));
          if (t == Sz - 1)
            dout[Bz * Sz + ((size_t)layer * Bz + brow) * Hz + col] = v;
        }
      }
      if (layer == Lz - 1) {
#pragma unroll
        for (int i = 0; i < 4; ++i) {
          float pv = hv[0][i] * wv[0] + hv[1][i] * wv[1] + hv[2][i] * wv[2] + hv[3][i] * wv[3];
          pv += __shfl_xor(pv, 1);
          pv += __shfl_xor(pv, 2);
          pv += __shfl_xor(pv, 4);
          pv += __shfl_xor(pv, 8);
          if (cc == 0) {
            const int brow = wav * 16 + gg * 4 + i;
            atomicAdd(&dout[(size_t)brow * Sz + t], pv);
          }
        }
      }
      // ---- release: drain write-through stores, then own-counter RMW
      asm volatile("s_waitcnt vmcnt(0)" ::: "memory");
      __syncthreads();
      if (tid == 0)
        __hip_atomic_fetch_add(Cown, 1, __ATOMIC_RELEASE, __HIP_MEMORY_SCOPE_AGENT);
    }
  } else {
    // ================= xproj worker =================
    const int jx = bid - 96;
    const int xc0 = jx << 6;  // 64 cols of H
    {
      const unsigned short* wsrc = Wihbf + ((size_t)xc0 << 9);
      for (int i = 0; i < 16; ++i) {
        const int off = (i * 256 + tid) * 8;
        __builtin_amdgcn_global_load_lds(wsrc + off, Wl + off, 16, 0, 0);
      }
      asm volatile("s_waitcnt vmcnt(0)" ::: "memory");
    }
    __syncthreads();
    const int ksw = (cc & 7) << 3;
    const int gg8 = gg << 3;
    int* Xown = &Xc[jx * CPAD];

    for (int tx = 0; tx < Sz; ++tx) {
      if (tx >= 4) {  // xq ring WAR guard: lanes 0-15 poll layer-0 WGs
        if (wav == 0) {
          const int* gp = (lane < 16) ? &C[(0 * 16 + lane) * CPAD] : nullptr;
          const int tgt = tx - 3;
          for (;;) {
            bool ok = true;
            if (gp)
              ok = __hip_atomic_load(gp, __ATOMIC_RELAXED, __HIP_MEMORY_SCOPE_AGENT) >= tgt;
            if (__all(ok)) break;
            __builtin_amdgcn_s_sleep(1);
          }
        }
        __syncthreads();
      }
      const float* xrow = x + ((size_t)ra * Sz + tx) * Iz + gg8;
      f32x4 acc[4];
#pragma unroll
      for (int n = 0; n < 4; ++n) acc[n] = (f32x4){0.f, 0.f, 0.f, 0.f};
      float4 xr[3][4];
#pragma unroll
      for (int c = 0; c < 2; ++c)
#pragma unroll
        for (int q = 0; q < 2; ++q) {
          xr[c][2 * q + 0] = *(const float4*)(xrow + c * 64 + q * 32);
          xr[c][2 * q + 1] = *(const float4*)(xrow + c * 64 + q * 32 + 4);
        }
#pragma unroll
      for (int c = 0; c < 8; ++c) {
        if (c + 2 < 8) {
          const int s2 = (c + 2) % 3;
#pragma unroll
          for (int q = 0; q < 2; ++q) {
            xr[s2][2 * q + 0] = *(const float4*)(xrow + (c + 2) * 64 + q * 32);
            xr[s2][2 * q + 1] = *(const float4*)(xrow + (c + 2) * 64 + q * 32 + 4);
          }
        }
        const int s = c % 3;
#pragma unroll
        for (int ks = 0; ks < 2; ++ks) {
          const float4 f0 = xr[s][2 * ks + 0];
          const float4 f1 = xr[s][2 * ks + 1];
          uint4 pk;
          pk.x = pkrnd(f0.x, f0.y);
          pk.y = pkrnd(f0.z, f0.w);
          pk.z = pkrnd(f1.x, f1.y);
          pk.w = pkrnd(f1.z, f1.w);
          const bf16x8 af = BC(pk);
          const int kof = c * 64 + ((ks * 32 + gg8) ^ ksw);
#pragma unroll
          for (int n = 0; n < 4; ++n) {
            const bf16x8 bf = *(const bf16x8*)(Wl + (n * 16 + cc) * 512 + kof);
            acc[n] = MFMA(af, bf, acc[n]);
          }
        }
      }
      float* xdst = xq + (size_t)(tx & 3) * (Bz * Hz);
#pragma unroll
      for (int n = 0; n < 4; ++n)
#pragma unroll
        for (int i = 0; i < 4; ++i) {
          const int brow = wav * 16 + gg * 4 + i;
          stf_llc(xdst + (size_t)brow * Hz + xc0 + n * 16 + cc, acc[n][i]);
        }
      asm volatile("s_waitcnt vmcnt(0)" ::: "memory");
      __syncthreads();
      if (tid == 0)
        __hip_atomic_fetch_add(Xown, 1, __ATOMIC_RELEASE, __HIP_MEMORY_SCOPE_AGENT);
    }
  }
}

extern "C" void kernel_launch(void* const* d_in, const int* in_sizes, int n_in,
                              void* d_out, int out_size, void* d_ws, size_t ws_size,
                              hipStream_t stream) {
  (void)in_sizes; (void)n_in; (void)out_size; (void)ws_size;
  const float* x    = (const float*)d_in[0];
  const float* wih  = (const float*)d_in[1];
  const float* bih  = (const float*)d_in[2];
  const float* whh  = (const float*)d_in[3];
  const float* bhh  = (const float*)d_in[4];
  const float* wout = (const float*)d_in[5];
  const float* bout = (const float*)d_in[6];
  float* out = (float*)d_out;
  char* ws = (char*)d_ws;
  // ws: [0,2M) Wbf | [2M,3M) Wihbf | [3M,6M) h ring bf16[4][L][B][H] |
  //     [6M,7M) xq ring f32[4][B][H] | [7M,+8K) bias0/1 |
  //     [7M+16K) counters C[96*CPAD], Xc[16*CPAD]
  unsigned short* Wbf   = (unsigned short*)(ws);
  unsigned short* Wihbf = (unsigned short*)(ws + ((size_t)2 << 20));
  unsigned short* hbuf  = (unsigned short*)(ws + ((size_t)3 << 20));
  float* xq    = (float*)(ws + ((size_t)6 << 20));
  float* bias0 = (float*)(ws + ((size_t)7 << 20));
  float* bias1 = bias0 + Hz;
  int* C  = (int*)(ws + ((size_t)7 << 20) + 16384);  // 96 cachelines
  int* Xc = C + 96 * CPAD;                           // 16 cachelines
  const int nflags = (96 + 16) * CPAD;

  (void)hipFuncSetAttribute((const void*)rnn_kernel,
                            hipFuncAttributeMaxDynamicSharedMemorySize, 131072);
  (void)hipGetLastError();

  hipLaunchKernelGGL(init_kernel, dim3(1024), dim3(256), 0, stream,
                     wih, bih, whh, bhh, bout, Wbf, Wihbf,
                     (unsigned int*)hbuf, bias0, bias1, out, C, nflags);
  hipLaunchKernelGGL(rnn_kernel, dim3(112), dim3(256), 131072, stream,
                     x, Wbf, Wihbf, hbuf, xq, bias0, bias1, wout, out, C, Xc);
}

// Round 16
// 4189.253 us; speedup vs baseline: 2.0324x; 1.6423x over previous
//
#include <hip/hip_runtime.h>

#define Bz 64
#define Sz 512
#define Iz 512
#define Hz 1024
#define Lz 6
#define CPAD 32   // ints per counter cacheline (128 B)

typedef __attribute__((ext_vector_type(8))) short bf16x8;
typedef __attribute__((ext_vector_type(4))) float f32x4;
typedef __attribute__((ext_vector_type(4))) unsigned u32x4;

__device__ __forceinline__ unsigned short f2bf(float f) {
  unsigned u = __float_as_uint(f);
  u += 0x7fffu + ((u >> 16) & 1u);
  return (unsigned short)(u >> 16);
}
__device__ __forceinline__ unsigned pkrnd(float lo, float hi) {
  return ((__float_as_uint(lo) + 0x8000u) >> 16) |
         ((__float_as_uint(hi) + 0x8000u) & 0xffff0000u);
}

// ---- asm helpers: LLC-direct (sc0 sc1 = bypass L1+L2) dataflow ----
template <int N>
__device__ __forceinline__ void vmwait() {
  asm volatile("s_waitcnt vmcnt(%0)" ::"n"(N) : "memory");
  __builtin_amdgcn_sched_barrier(0);
}
template <int OFF>
__device__ __forceinline__ uint4 ld16llc(const void* p) {
  uint4 r;
  asm volatile("global_load_dwordx4 %0, %1, off offset:%2 sc0 sc1"
               : "=&v"(r) : "v"(p), "n"(OFF));
  return r;
}
__device__ __forceinline__ float ldf_llc(const float* p) {
  float r;
  asm volatile("global_load_dword %0, %1, off sc0 sc1" : "=&v"(r) : "v"(p));
  return r;
}
__device__ __forceinline__ void stf_llc(float* p, float v) {
  asm volatile("global_store_dword %0, %1, off sc0 sc1" ::"v"(p), "v"(v) : "memory");
}
__device__ __forceinline__ void st16llc(void* p, u32x4 v) {  // ext-vector: valid asm input
  asm volatile("global_store_dwordx4 %0, %1, off sc0 sc1" ::"v"(p), "v"(v) : "memory");
}

#define MFMA(a, b, c) __builtin_amdgcn_mfma_f32_16x16x32_bf16(a, b, c, 0, 0, 0)
#define BC(u) __builtin_bit_cast(bf16x8, u)

// Weights pre-swizzled as before. h is stored K-MAJOR-TILED:
//   element (row r, col k) of a [Bz][Hz] slot lives at ((k>>3)*64 + r)*8 + (k&7)
// so a wave's A-fragment gather (16 rows x 16B) is 4 contiguous 256B runs
// (8 fully-used 128B lines/instr instead of 16 half-used).
__global__ void init_kernel(const float* __restrict__ wih, const float* __restrict__ bih,
                            const float* __restrict__ whh, const float* __restrict__ bhh,
                            const float* __restrict__ bout,
                            unsigned short* __restrict__ Wbf,
                            unsigned short* __restrict__ Wihbf,
                            unsigned int* __restrict__ hbuf32,
                            float* __restrict__ bias0, float* __restrict__ bias1,
                            float* __restrict__ out, int* __restrict__ flags, int nflags) {
  int tid = blockIdx.x * blockDim.x + threadIdx.x;
  int nt = gridDim.x * blockDim.x;
  for (int i = tid; i < Hz * Hz; i += nt) {
    int col = i >> 10, k = i & 1023;
    Wbf[(col << 10) | (k ^ ((col & 7) << 3))] = f2bf(whh[i]);
  }
  for (int i = tid; i < Hz * Iz; i += nt) {
    int col = i >> 9, k = i & 511;
    Wihbf[(col << 9) | (k ^ ((col & 7) << 3))] = f2bf(wih[i]);
  }
  for (int i = tid; i < (4 * Lz * Bz * Hz) / 2; i += nt) hbuf32[i] = 0u;  // 4-slot ring
  for (int i = tid; i < Hz; i += nt) {
    bias0[i] = bih[i] + bhh[i];   // layer 0
    bias1[i] = 2.0f * bhh[i];     // layers 1..5 (bias added twice in ref)
  }
  float b0 = bout[0];
  for (int i = tid; i < Bz * Sz; i += nt) out[i] = b0;
  for (int i = tid; i < nflags; i += nt) flags[i] = 0;
}

// Dual-stream cell GEMM: 16 rows(this wave) x 64 cols x K=1024, 8-ahead ring.
// Chunk c covers kgroups 8c..8c+7: a-part = kgroup 8c+gg (byte c*8192),
// b-part = kgroup 8c+4+gg (byte c*8192+4096), from the k-major h layout.
__device__ __forceinline__ void cell_gemm_d(const unsigned short* pA, const unsigned short* pB,
                                            const unsigned short* Wl, int cc, int gg,
                                            f32x4 acc[4]) {
  const int ksw = (cc & 7) << 3;
  const int gg8 = gg << 3;
  const unsigned short* Wl0 = Wl + (0 * 16 + cc) * 1024;
  const unsigned short* Wl1 = Wl + (1 * 16 + cc) * 1024;
  const unsigned short* Wl2 = Wl + (2 * 16 + cc) * 1024;
  const unsigned short* Wl3 = Wl + (3 * 16 + cc) * 1024;
  uint4 A1a[16], A1b[16], A2a[16], A2b[16];
#define ISSD(c) { const size_t d_ = (size_t)(c) * 8192; \
    A1a[c] = ld16llc<0>((const char*)pA + d_); \
    A1b[c] = ld16llc<0>((const char*)pA + d_ + 4096); \
    A2a[c] = ld16llc<0>((const char*)pB + d_); \
    A2b[c] = ld16llc<0>((const char*)pB + d_ + 4096); }
#define CONS_KS(kofv, AFa, AFb) { \
    const int kof = (kofv); \
    const bf16x8 bA = *(const bf16x8*)(Wl0 + kof); \
    const bf16x8 bB = *(const bf16x8*)(Wl1 + kof); \
    const bf16x8 bC = *(const bf16x8*)(Wl2 + kof); \
    const bf16x8 bD = *(const bf16x8*)(Wl3 + kof); \
    acc[0] = MFMA(AFa, bA, acc[0]); acc[1] = MFMA(AFa, bB, acc[1]); \
    acc[2] = MFMA(AFa, bC, acc[2]); acc[3] = MFMA(AFa, bD, acc[3]); \
    acc[0] = MFMA(AFb, bA, acc[0]); acc[1] = MFMA(AFb, bB, acc[1]); \
    acc[2] = MFMA(AFb, bC, acc[2]); acc[3] = MFMA(AFb, bD, acc[3]); }
#define CONSD(c) { \
    vmwait<4 * ((((c) + 8) < 16) ? 8 : 15 - (c))>(); \
    CONS_KS((c) * 64 + (gg8 ^ ksw), BC(A1a[c]), BC(A2a[c])); \
    CONS_KS((c) * 64 + ((32 + gg8) ^ ksw), BC(A1b[c]), BC(A2b[c])); }
  ISSD(0) ISSD(1) ISSD(2) ISSD(3) ISSD(4) ISSD(5) ISSD(6) ISSD(7)
  ISSD(8)  CONSD(0)  ISSD(9)  CONSD(1)  ISSD(10) CONSD(2)
  ISSD(11) CONSD(3)  ISSD(12) CONSD(4)  ISSD(13) CONSD(5)
  ISSD(14) CONSD(6)  ISSD(15) CONSD(7)
  CONSD(8) CONSD(9) CONSD(10) CONSD(11) CONSD(12) CONSD(13) CONSD(14) CONSD(15)
#undef ISSD
#undef CONSD
#undef CONS_KS
}

// Single-stream variant (layer 0): A1 = h[0]_{t-1}, 8-ahead ring.
__device__ __forceinline__ void cell_gemm_s(const unsigned short* pA,
                                            const unsigned short* Wl, int cc, int gg,
                                            f32x4 acc[4]) {
  const int ksw = (cc & 7) << 3;
  const int gg8 = gg << 3;
  const unsigned short* Wl0 = Wl + (0 * 16 + cc) * 1024;
  const unsigned short* Wl1 = Wl + (1 * 16 + cc) * 1024;
  const unsigned short* Wl2 = Wl + (2 * 16 + cc) * 1024;
  const unsigned short* Wl3 = Wl + (3 * 16 + cc) * 1024;
  uint4 A1a[16], A1b[16];
#define ISSS(c) { const size_t d_ = (size_t)(c) * 8192; \
    A1a[c] = ld16llc<0>((const char*)pA + d_); \
    A1b[c] = ld16llc<0>((const char*)pA + d_ + 4096); }
#define CONS_K1(kofv, AF) { \
    const int kof = (kofv); \
    const bf16x8 bA = *(const bf16x8*)(Wl0 + kof); \
    const bf16x8 bB = *(const bf16x8*)(Wl1 + kof); \
    const bf16x8 bC = *(const bf16x8*)(Wl2 + kof); \
    const bf16x8 bD = *(const bf16x8*)(Wl3 + kof); \
    acc[0] = MFMA(AF, bA, acc[0]); acc[1] = MFMA(AF, bB, acc[1]); \
    acc[2] = MFMA(AF, bC, acc[2]); acc[3] = MFMA(AF, bD, acc[3]); }
#define CONSS(c) { \
    vmwait<2 * ((((c) + 8) < 16) ? 8 : 15 - (c))>(); \
    CONS_K1((c) * 64 + (gg8 ^ ksw), BC(A1a[c])); \
    CONS_K1((c) * 64 + ((32 + gg8) ^ ksw), BC(A1b[c])); }
  ISSS(0) ISSS(1) ISSS(2) ISSS(3) ISSS(4) ISSS(5) ISSS(6) ISSS(7)
  ISSS(8)  CONSS(0)  ISSS(9)  CONSS(1)  ISSS(10) CONSS(2)  ISSS(11) CONSS(3)
  ISSS(12) CONSS(4)  ISSS(13) CONSS(5)  ISSS(14) CONSS(6)  ISSS(15) CONSS(7)
  CONSS(8) CONSS(9) CONSS(10) CONSS(11) CONSS(12) CONSS(13) CONSS(14) CONSS(15)
#undef ISSS
#undef CONSS
#undef CONS_K1
}

// Persistent self-timed wavefront kernel (R14 structure + k-major h layout +
// LDS-transposed vectorized h writeback). Sync/gates identical to R14.
__global__ __launch_bounds__(256, 1) void rnn_kernel(
    const float* __restrict__ x,
    const unsigned short* __restrict__ Wbf,
    const unsigned short* __restrict__ Wihbf,
    unsigned short* __restrict__ hbuf, float* __restrict__ xq,
    const float* __restrict__ bias0, const float* __restrict__ bias1,
    const float* __restrict__ wout,
    float* __restrict__ dout, int* __restrict__ C, int* __restrict__ Xc) {
  extern __shared__ char lds[];
  unsigned short* Wl = (unsigned short*)lds;
  unsigned short* hT = (unsigned short*)(lds + 131072);  // [64][72] bf16 transpose tile

  const int bid = blockIdx.x;
  const int tid = threadIdx.x;
  const int lane = tid & 63;
  const int wav = tid >> 6;
  const int cc = lane & 15;
  const int gg = lane >> 4;
  const int ra = wav * 16 + cc;  // A row this lane gathers

  if (bid < 96) {
    // ================= layer worker =================
    const int layer = bid >> 4;
    const int jself = bid & 15;
    const int c0 = jself << 6;  // 64 output cols
    {
      const unsigned short* wsrc = Wbf + ((size_t)c0 << 10);
      for (int i = 0; i < 32; ++i) {
        const int off = (i * 256 + tid) * 8;
        __builtin_amdgcn_global_load_lds(wsrc + off, Wl + off, 16, 0, 0);
      }
      asm volatile("s_waitcnt vmcnt(0)" ::: "memory");
    }
    __syncthreads();
    float bv[4], wv[4];
#pragma unroll
    for (int n = 0; n < 4; ++n) {
      const int col = c0 + n * 16 + cc;
      bv[n] = (layer == 0) ? bias0[col] : bias1[col];
      wv[n] = (layer == Lz - 1) ? wout[col] : 0.f;
    }
    int* Cown = &C[(layer * 16 + jself) * CPAD];
    // writeback assignment: this thread stores (row wr, kgroup wg) x2
    const int wr0 = (tid * 2) >> 3, wg0 = (tid * 2) & 7;
    const int wr1 = (tid * 2 + 1) >> 3, wg1 = (tid * 2 + 1) & 7;

    for (int t = 0; t < Sz; ++t) {
      const int b = t + layer;
      // ---- WG-wide gate (R14-exact)
      if (wav == 0) {
        const int* gp = nullptr;
        int tgt = 0;
        const int j = lane & 15;
        if (lane < 16) {
          if (layer > 0) { gp = &C[((layer - 1) * 16 + j) * CPAD]; tgt = t + 1; }
          else           { gp = &Xc[j * CPAD];                      tgt = t + 1; }
        } else if (lane < 32) {
          if (t >= 1)    { gp = &C[(layer * 16 + j) * CPAD];        tgt = t; }
        } else if (lane < 48) {
          if (layer < Lz - 1 && t >= 4) { gp = &C[((layer + 1) * 16 + j) * CPAD]; tgt = t - 3; }
        }
        for (;;) {
          bool ok = true;
          if (gp)
            ok = __hip_atomic_load(gp, __ATOMIC_RELAXED, __HIP_MEMORY_SCOPE_AGENT) >= tgt;
          if (__all(ok)) break;
          __builtin_amdgcn_s_sleep(1);
        }
      }
      __syncthreads();

      const unsigned short* hrd = hbuf + (size_t)(b & 3) * (Lz * Bz * Hz);
      unsigned short* hwr = hbuf + (size_t)((b + 1) & 3) * (Lz * Bz * Hz);

      f32x4 acc[4];
#pragma unroll
      for (int n = 0; n < 4; ++n) acc[n] = (f32x4){0.f, 0.f, 0.f, 0.f};
      if (layer == 0) {
        const unsigned short* pA = hrd + ((size_t)gg * 64 + ra) * 8;
        cell_gemm_s(pA, Wl, cc, gg, acc);
      } else {
        const unsigned short* pA =
            hrd + (size_t)(layer - 1) * (Bz * Hz) + ((size_t)gg * 64 + ra) * 8;
        const unsigned short* pB =
            hrd + (size_t)layer * (Bz * Hz) + ((size_t)gg * 64 + ra) * 8;
        cell_gemm_d(pA, pB, Wl, cc, gg, acc);
      }

      // ---- epilogue (layer 0: add xproj, LLC-direct loads)
      float xv[16];
      if (layer == 0) {
        const float* xb = xq + (size_t)(t & 3) * (Bz * Hz);
#pragma unroll
        for (int n = 0; n < 4; ++n)
#pragma unroll
          for (int i = 0; i < 4; ++i) {
            const int brow = wav * 16 + gg * 4 + i;
            xv[n * 4 + i] = ldf_llc(xb + (size_t)brow * Hz + c0 + n * 16 + cc);
          }
        vmwait<0>();
      }
      float hv[4][4];
#pragma unroll
      for (int n = 0; n < 4; ++n) {
        const int col = c0 + n * 16 + cc;
#pragma unroll
        for (int i = 0; i < 4; ++i) {
          const int brow = wav * 16 + gg * 4 + i;
          float z = acc[n][i] + bv[n];
          if (layer == 0) z += xv[n * 4 + i];
          const float v = tanhf(z);
          hv[n][i] = v;
          hT[brow * 72 + n * 16 + cc] = f2bf(v);   // LDS transpose tile
          if (t == Sz - 1)
            dout[Bz * Sz + ((size_t)layer * Bz + brow) * Hz + col] = v;
        }
      }
      if (layer == Lz - 1) {
#pragma unroll
        for (int i = 0; i < 4; ++i) {
          float pv = hv[0][i] * wv[0] + hv[1][i] * wv[1] + hv[2][i] * wv[2] + hv[3][i] * wv[3];
          pv += __shfl_xor(pv, 1);
          pv += __shfl_xor(pv, 2);
          pv += __shfl_xor(pv, 4);
          pv += __shfl_xor(pv, 8);
          if (cc == 0) {
            const int brow = wav * 16 + gg * 4 + i;
            atomicAdd(&dout[(size_t)brow * Sz + t], pv);
          }
        }
      }
      __syncthreads();  // hT complete
      // ---- vectorized h writeback: 2x (ds_read_b128 + 16B LLC store)/thread
      {
        unsigned short* hwb = hwr + (size_t)layer * (Bz * Hz) + (size_t)c0 * 64;
        const u32x4 v0 = *(const u32x4*)&hT[wr0 * 72 + wg0 * 8];
        st16llc(hwb + (size_t)wg0 * 512 + wr0 * 8, v0);
        const u32x4 v1 = *(const u32x4*)&hT[wr1 * 72 + wg1 * 8];
        st16llc(hwb + (size_t)wg1 * 512 + wr1 * 8, v1);
      }
      // ---- release: drain stores, then own-counter RMW
      asm volatile("s_waitcnt vmcnt(0)" ::: "memory");
      __syncthreads();
      if (tid == 0)
        __hip_atomic_fetch_add(Cown, 1, __ATOMIC_RELEASE, __HIP_MEMORY_SCOPE_AGENT);
    }
  } else {
    // ================= xproj worker (R14-exact) =================
    const int jx = bid - 96;
    const int xc0 = jx << 6;  // 64 cols of H
    {
      const unsigned short* wsrc = Wihbf + ((size_t)xc0 << 9);
      for (int i = 0; i < 16; ++i) {
        const int off = (i * 256 + tid) * 8;
        __builtin_amdgcn_global_load_lds(wsrc + off, Wl + off, 16, 0, 0);
      }
      asm volatile("s_waitcnt vmcnt(0)" ::: "memory");
    }
    __syncthreads();
    const int ksw = (cc & 7) << 3;
    const int gg8 = gg << 3;
    int* Xown = &Xc[jx * CPAD];

    for (int tx = 0; tx < Sz; ++tx) {
      if (tx >= 4) {
        if (wav == 0) {
          const int* gp = (lane < 16) ? &C[(0 * 16 + lane) * CPAD] : nullptr;
          const int tgt = tx - 3;
          for (;;) {
            bool ok = true;
            if (gp)
              ok = __hip_atomic_load(gp, __ATOMIC_RELAXED, __HIP_MEMORY_SCOPE_AGENT) >= tgt;
            if (__all(ok)) break;
            __builtin_amdgcn_s_sleep(1);
          }
        }
        __syncthreads();
      }
      const float* xrow = x + ((size_t)ra * Sz + tx) * Iz + gg8;
      f32x4 acc[4];
#pragma unroll
      for (int n = 0; n < 4; ++n) acc[n] = (f32x4){0.f, 0.f, 0.f, 0.f};
      float4 xr[3][4];
#pragma unroll
      for (int c = 0; c < 2; ++c)
#pragma unroll
        for (int q = 0; q < 2; ++q) {
          xr[c][2 * q + 0] = *(const float4*)(xrow + c * 64 + q * 32);
          xr[c][2 * q + 1] = *(const float4*)(xrow + c * 64 + q * 32 + 4);
        }
#pragma unroll
      for (int c = 0; c < 8; ++c) {
        if (c + 2 < 8) {
          const int s2 = (c + 2) % 3;
#pragma unroll
          for (int q = 0; q < 2; ++q) {
            xr[s2][2 * q + 0] = *(const float4*)(xrow + (c + 2) * 64 + q * 32);
            xr[s2][2 * q + 1] = *(const float4*)(xrow + (c + 2) * 64 + q * 32 + 4);
          }
        }
        const int s = c % 3;
#pragma unroll
        for (int ks = 0; ks < 2; ++ks) {
          const float4 f0 = xr[s][2 * ks + 0];
          const float4 f1 = xr[s][2 * ks + 1];
          uint4 pk;
          pk.x = pkrnd(f0.x, f0.y);
          pk.y = pkrnd(f0.z, f0.w);
          pk.z = pkrnd(f1.x, f1.y);
          pk.w = pkrnd(f1.z, f1.w);
          const bf16x8 af = BC(pk);
          const int kof = c * 64 + ((ks * 32 + gg8) ^ ksw);
#pragma unroll
          for (int n = 0; n < 4; ++n) {
            const bf16x8 bf = *(const bf16x8*)(Wl + (n * 16 + cc) * 512 + kof);
            acc[n] = MFMA(af, bf, acc[n]);
          }
        }
      }
      float* xdst = xq + (size_t)(tx & 3) * (Bz * Hz);
#pragma unroll
      for (int n = 0; n < 4; ++n)
#pragma unroll
        for (int i = 0; i < 4; ++i) {
          const int brow = wav * 16 + gg * 4 + i;
          stf_llc(xdst + (size_t)brow * Hz + xc0 + n * 16 + cc, acc[n][i]);
        }
      asm volatile("s_waitcnt vmcnt(0)" ::: "memory");
      __syncthreads();
      if (tid == 0)
        __hip_atomic_fetch_add(Xown, 1, __ATOMIC_RELEASE, __HIP_MEMORY_SCOPE_AGENT);
    }
  }
}

extern "C" void kernel_launch(void* const* d_in, const int* in_sizes, int n_in,
                              void* d_out, int out_size, void* d_ws, size_t ws_size,
                              hipStream_t stream) {
  (void)in_sizes; (void)n_in; (void)out_size; (void)ws_size;
  const float* x    = (const float*)d_in[0];
  const float* wih  = (const float*)d_in[1];
  const float* bih  = (const float*)d_in[2];
  const float* whh  = (const float*)d_in[3];
  const float* bhh  = (const float*)d_in[4];
  const float* wout = (const float*)d_in[5];
  const float* bout = (const float*)d_in[6];
  float* out = (float*)d_out;
  char* ws = (char*)d_ws;
  // ws: [0,2M) Wbf | [2M,3M) Wihbf | [3M,6M) h ring bf16[4][L][B*H k-major] |
  //     [6M,7M) xq ring f32[4][B][H] | [7M,+8K) bias0/1 |
  //     [7M+16K) counters C[96*CPAD], Xc[16*CPAD]
  unsigned short* Wbf   = (unsigned short*)(ws);
  unsigned short* Wihbf = (unsigned short*)(ws + ((size_t)2 << 20));
  unsigned short* hbuf  = (unsigned short*)(ws + ((size_t)3 << 20));
  float* xq    = (float*)(ws + ((size_t)6 << 20));
  float* bias0 = (float*)(ws + ((size_t)7 << 20));
  float* bias1 = bias0 + Hz;
  int* C  = (int*)(ws + ((size_t)7 << 20) + 16384);  // 96 cachelines
  int* Xc = C + 96 * CPAD;                           // 16 cachelines
  const int nflags = (96 + 16) * CPAD;

  (void)hipFuncSetAttribute((const void*)rnn_kernel,
                            hipFuncAttributeMaxDynamicSharedMemorySize, 140544);
  (void)hipGetLastError();

  hipLaunchKernelGGL(init_kernel, dim3(1024), dim3(256), 0, stream,
                     wih, bih, whh, bhh, bout, Wbf, Wihbf,
                     (unsigned int*)hbuf, bias0, bias1, out, C, nflags);
  hipLaunchKernelGGL(rnn_kernel, dim3(112), dim3(256), 140544, stream,
                     x, Wbf, Wihbf, hbuf, xq, bias0, bias1, wout, out, C, Xc);
}